// Round 1
// baseline (543.376 us; speedup 1.0000x reference)
//
#include <hip/hip_runtime.h>
#include <math.h>

// f(p) = log(2) - softplus(-p), numerically stable:
// softplus(x) = max(x,0) + log1p(exp(-|x|))
__device__ __forceinline__ float jsd_pos(float p) {
    float sp = fmaxf(-p, 0.0f) + log1pf(expf(-fabsf(p)));
    return 0.69314718055994531f - sp;
}

// One wave (64 lanes) per node. D=256 floats per row = 64 float4 -> one
// float4 per lane per row. 4 waves per 256-thread block.
__global__ __launch_bounds__(256) void jsd_dot_kernel(
    const int*   __restrict__ b1,
    const int*   __restrict__ b2,
    const float* __restrict__ z1,
    const float* __restrict__ z2,
    const float* __restrict__ g1,
    const float* __restrict__ g2,
    float*       __restrict__ acc)   // acc[0]=sum (d1^2), acc[1]=sum (d2^2)
{
    const int wave = threadIdx.x >> 6;
    const int lane = threadIdx.x & 63;
    const int node = blockIdx.x * 4 + wave;   // N divisible by 4

    const int i1 = b1[node];
    const int i2 = b2[node];

    const float4* z1v  = (const float4*)(z1 + (size_t)node * 256);
    const float4* z2v  = (const float4*)(z2 + (size_t)node * 256);
    const float4* g11v = (const float4*)(g1 + (size_t)i1 * 256);
    const float4* g21v = (const float4*)(g2 + (size_t)i1 * 256);
    const float4* g22v = (const float4*)(g2 + (size_t)i2 * 256);
    const float4* g12v = (const float4*)(g1 + (size_t)i2 * 256);

    float4 a1  = z1v[lane];
    float4 a2  = z2v[lane];
    float4 w11 = g11v[lane];
    float4 w12 = g21v[lane];
    float4 w22 = g22v[lane];
    float4 w21 = g12v[lane];

    float s11 = a1.x*w11.x + a1.y*w11.y + a1.z*w11.z + a1.w*w11.w;
    float c12 = a1.x*w12.x + a1.y*w12.y + a1.z*w12.z + a1.w*w12.w;
    float s22 = a2.x*w22.x + a2.y*w22.y + a2.z*w22.z + a2.w*w22.w;
    float c21 = a2.x*w21.x + a2.y*w21.y + a2.z*w21.z + a2.w*w21.w;

    // 64-lane butterfly reduction of 4 partials
    #pragma unroll
    for (int off = 32; off >= 1; off >>= 1) {
        s11 += __shfl_down(s11, off, 64);
        c12 += __shfl_down(c12, off, 64);
        s22 += __shfl_down(s22, off, 64);
        c21 += __shfl_down(c21, off, 64);
    }

    __shared__ float blk[2];
    if (threadIdx.x == 0) { blk[0] = 0.0f; blk[1] = 0.0f; }
    __syncthreads();

    if (lane == 0) {
        float d1 = jsd_pos(s11) - jsd_pos(c12);
        float d2 = jsd_pos(s22) - jsd_pos(c21);
        atomicAdd(&blk[0], d1 * d1);
        atomicAdd(&blk[1], d2 * d2);
    }
    __syncthreads();

    if (threadIdx.x == 0) {
        atomicAdd(&acc[0], blk[0]);
        atomicAdd(&acc[1], blk[1]);
    }
}

__global__ void jsd_finalize_kernel(const float* __restrict__ acc,
                                    float* __restrict__ out)
{
    if (threadIdx.x == 0) {
        out[0] = sqrtf(acc[0]) + sqrtf(acc[1]);
    }
}

extern "C" void kernel_launch(void* const* d_in, const int* in_sizes, int n_in,
                              void* d_out, int out_size, void* d_ws, size_t ws_size,
                              hipStream_t stream) {
    const int*   b1 = (const int*)  d_in[0];
    const int*   b2 = (const int*)  d_in[1];
    const float* z1 = (const float*)d_in[2];
    const float* z2 = (const float*)d_in[3];
    const float* g1 = (const float*)d_in[4];
    const float* g2 = (const float*)d_in[5];
    float* out = (float*)d_out;
    float* acc = (float*)d_ws;

    const int N = in_sizes[0];   // 65536

    // d_ws is re-poisoned to 0xAA before every launch — zero the accumulators.
    hipMemsetAsync(acc, 0, 2 * sizeof(float), stream);

    jsd_dot_kernel<<<N / 4, 256, 0, stream>>>(b1, b2, z1, z2, g1, g2, acc);
    jsd_finalize_kernel<<<1, 64, 0, stream>>>(acc, out);
}

// Round 2
// 177.474 us; speedup vs baseline: 3.0617x; 3.0617x over previous
//
#include <hip/hip_runtime.h>
#include <math.h>

// f(p) = log(2) - softplus(-p), numerically stable:
// softplus(x) = max(x,0) + log1p(exp(-|x|))
__device__ __forceinline__ float jsd_pos(float p) {
    float sp = fmaxf(-p, 0.0f) + log1pf(expf(-fabsf(p)));
    return 0.69314718055994531f - sp;
}

#define NBLOCKS 2048
#define NODES_PER_WAVE 8   // 65536 nodes / (2048 blocks * 4 waves)

// One wave (64 lanes) per group of 8 consecutive nodes. D=256 floats per row
// = 64 float4 -> one float4 per lane per row. 4 waves per 256-thread block.
// No global atomics: per-block partials written to ws, reduced by 2nd kernel.
__global__ __launch_bounds__(256) void jsd_dot_kernel(
    const int*   __restrict__ b1,
    const int*   __restrict__ b2,
    const float* __restrict__ z1,
    const float* __restrict__ z2,
    const float* __restrict__ g1,
    const float* __restrict__ g2,
    float*       __restrict__ partials)   // [NBLOCKS*2]
{
    const int wave = threadIdx.x >> 6;
    const int lane = threadIdx.x & 63;
    const int w    = blockIdx.x * 4 + wave;     // global wave id

    float acc1 = 0.0f, acc2 = 0.0f;

    #pragma unroll
    for (int j = 0; j < NODES_PER_WAVE; ++j) {
        const int node = w * NODES_PER_WAVE + j;

        const int i1 = b1[node];
        const int i2 = b2[node];

        const float4 a1  = ((const float4*)(z1 + (size_t)node * 256))[lane];
        const float4 a2  = ((const float4*)(z2 + (size_t)node * 256))[lane];
        const float4 w11 = ((const float4*)(g1 + (size_t)i1 * 256))[lane];
        const float4 w12 = ((const float4*)(g2 + (size_t)i1 * 256))[lane];
        const float4 w22 = ((const float4*)(g2 + (size_t)i2 * 256))[lane];
        const float4 w21 = ((const float4*)(g1 + (size_t)i2 * 256))[lane];

        float s11 = a1.x*w11.x + a1.y*w11.y + a1.z*w11.z + a1.w*w11.w;
        float c12 = a1.x*w12.x + a1.y*w12.y + a1.z*w12.z + a1.w*w12.w;
        float s22 = a2.x*w22.x + a2.y*w22.y + a2.z*w22.z + a2.w*w22.w;
        float c21 = a2.x*w21.x + a2.y*w21.y + a2.z*w21.z + a2.w*w21.w;

        // 64-lane butterfly reduction of 4 partials
        #pragma unroll
        for (int off = 32; off >= 1; off >>= 1) {
            s11 += __shfl_down(s11, off, 64);
            c12 += __shfl_down(c12, off, 64);
            s22 += __shfl_down(s22, off, 64);
            c21 += __shfl_down(c21, off, 64);
        }

        if (lane == 0) {
            float d1 = jsd_pos(s11) - jsd_pos(c12);
            float d2 = jsd_pos(s22) - jsd_pos(c21);
            acc1 += d1 * d1;
            acc2 += d2 * d2;
        }
    }

    __shared__ float s1[4], s2[4];
    if (lane == 0) { s1[wave] = acc1; s2[wave] = acc2; }
    __syncthreads();

    if (threadIdx.x == 0) {
        partials[blockIdx.x * 2 + 0] = s1[0] + s1[1] + s1[2] + s1[3];
        partials[blockIdx.x * 2 + 1] = s2[0] + s2[1] + s2[2] + s2[3];
    }
}

__global__ __launch_bounds__(256) void jsd_reduce_kernel(
    const float* __restrict__ partials,
    float*       __restrict__ out)
{
    const int tid  = threadIdx.x;
    const int wave = tid >> 6;
    const int lane = tid & 63;

    float a = 0.0f, b = 0.0f;
    for (int i = tid; i < NBLOCKS; i += 256) {
        a += partials[i * 2 + 0];
        b += partials[i * 2 + 1];
    }

    #pragma unroll
    for (int off = 32; off >= 1; off >>= 1) {
        a += __shfl_down(a, off, 64);
        b += __shfl_down(b, off, 64);
    }

    __shared__ float s1[4], s2[4];
    if (lane == 0) { s1[wave] = a; s2[wave] = b; }
    __syncthreads();

    if (tid == 0) {
        float t1 = s1[0] + s1[1] + s1[2] + s1[3];
        float t2 = s2[0] + s2[1] + s2[2] + s2[3];
        out[0] = sqrtf(t1) + sqrtf(t2);
    }
}

extern "C" void kernel_launch(void* const* d_in, const int* in_sizes, int n_in,
                              void* d_out, int out_size, void* d_ws, size_t ws_size,
                              hipStream_t stream) {
    const int*   b1 = (const int*)  d_in[0];
    const int*   b2 = (const int*)  d_in[1];
    const float* z1 = (const float*)d_in[2];
    const float* z2 = (const float*)d_in[3];
    const float* g1 = (const float*)d_in[4];
    const float* g2 = (const float*)d_in[5];
    float* out      = (float*)d_out;
    float* partials = (float*)d_ws;   // NBLOCKS*2 floats, fully overwritten

    jsd_dot_kernel<<<NBLOCKS, 256, 0, stream>>>(b1, b2, z1, z2, g1, g2, partials);
    jsd_reduce_kernel<<<1, 256, 0, stream>>>(partials, out);
}

// Round 3
// 159.289 us; speedup vs baseline: 3.4113x; 1.1142x over previous
//
#include <hip/hip_runtime.h>
#include <math.h>

// softplus(-p) = max(-p,0) + log(1+exp(-|p|)) ; fast intrinsics are fine:
// threshold is 135 absolute on a ~6752 output (2%), __logf/__expf rel err ~1e-6.
__device__ __forceinline__ float spn(float p) {
    return fmaxf(-p, 0.0f) + __logf(1.0f + __expf(-fabsf(p)));
}

// VALU-only reduction over a 16-lane row via DPP row_shr.
// After 4 rounds, lane 15 of each row holds the row sum (bound_ctrl=true
// shifts in zeros). No LDS pipe, no lgkmcnt waits.
__device__ __forceinline__ float dpp_shr_add(float x, float y_unused) { return x; }

__device__ __forceinline__ float row16_reduce(float x) {
    int xi;
    xi = __builtin_amdgcn_update_dpp(0, __builtin_bit_cast(int, x), 0x111, 0xf, 0xf, true);
    x += __builtin_bit_cast(float, xi);   // + lane-1
    xi = __builtin_amdgcn_update_dpp(0, __builtin_bit_cast(int, x), 0x112, 0xf, 0xf, true);
    x += __builtin_bit_cast(float, xi);   // + lane-2
    xi = __builtin_amdgcn_update_dpp(0, __builtin_bit_cast(int, x), 0x114, 0xf, 0xf, true);
    x += __builtin_bit_cast(float, xi);   // + lane-4
    xi = __builtin_amdgcn_update_dpp(0, __builtin_bit_cast(int, x), 0x118, 0xf, 0xf, true);
    x += __builtin_bit_cast(float, xi);   // + lane-8  -> lane15 = row sum
    return x;
}

__device__ __forceinline__ float dot4(float4 a, float4 b) {
    return a.x * b.x + a.y * b.y + a.z * b.z + a.w * b.w;
}

#define NBLOCKS 2048

// Quarter-wave (16 lanes) per node; 4 nodes in flight per wave; 2 groups
// per wave => 8 nodes/wave * 8192 waves = 65536 nodes.
// D=256 covered in 4 passes of 64 floats (one float4 per lane per pass),
// pass offsets fold into the 13-bit global_load imm offset field.
__global__ __launch_bounds__(256) void jsd_dot_kernel(
    const int*   __restrict__ b1,
    const int*   __restrict__ b2,
    const float* __restrict__ z1,
    const float* __restrict__ z2,
    const float* __restrict__ g1,
    const float* __restrict__ g2,
    float*       __restrict__ partials)   // [NBLOCKS*2]
{
    const int wave = threadIdx.x >> 6;
    const int lane = threadIdx.x & 63;
    const int q    = lane >> 4;   // quarter id: which of 4 nodes
    const int lq   = lane & 15;   // lane within quarter
    const int w    = blockIdx.x * 4 + wave;   // global wave id

    float acc1 = 0.0f, acc2 = 0.0f;

    #pragma unroll
    for (int g = 0; g < 2; ++g) {
        const int node = w * 8 + g * 4 + q;

        const int i1 = b1[node];   // 4 consecutive addrs per wave: 1 cacheline
        const int i2 = b2[node];

        const float4* z1p  = (const float4*)(z1 + (size_t)node * 256) + lq;
        const float4* z2p  = (const float4*)(z2 + (size_t)node * 256) + lq;
        const float4* g11p = (const float4*)(g1 + (size_t)i1 * 256) + lq;
        const float4* g21p = (const float4*)(g2 + (size_t)i1 * 256) + lq;
        const float4* g22p = (const float4*)(g2 + (size_t)i2 * 256) + lq;
        const float4* g12p = (const float4*)(g1 + (size_t)i2 * 256) + lq;

        float s11 = 0.0f, c12 = 0.0f, s22 = 0.0f, c21 = 0.0f;

        #pragma unroll
        for (int p = 0; p < 4; ++p) {
            // stride 16 float4 = 64 floats = one pass chunk; imm offsets 0/256/512/768B
            float4 a1  = z1p[p * 16];
            float4 a2  = z2p[p * 16];
            float4 w11 = g11p[p * 16];
            float4 w12 = g21p[p * 16];
            float4 w22 = g22p[p * 16];
            float4 w21 = g12p[p * 16];
            s11 += dot4(a1, w11);
            c12 += dot4(a1, w12);
            s22 += dot4(a2, w22);
            c21 += dot4(a2, w21);
        }

        // VALU-only reduction within each 16-lane quarter
        s11 = row16_reduce(s11);
        c12 = row16_reduce(c12);
        s22 = row16_reduce(s22);
        c21 = row16_reduce(c21);

        if (lq == 15) {
            // f(s)-f(c) = softplus(-c) - softplus(-s)
            float d1 = spn(c12) - spn(s11);
            float d2 = spn(c21) - spn(s22);
            acc1 += d1 * d1;
            acc2 += d2 * d2;
        }
    }

    // per-block combine: 16 quarter-lane accumulators per block
    __shared__ float s1[16], s2[16];
    if (lq == 15) {
        s1[wave * 4 + q] = acc1;
        s2[wave * 4 + q] = acc2;
    }
    __syncthreads();

    if (threadIdx.x == 0) {
        float t1 = 0.0f, t2 = 0.0f;
        #pragma unroll
        for (int i = 0; i < 16; ++i) { t1 += s1[i]; t2 += s2[i]; }
        partials[blockIdx.x * 2 + 0] = t1;
        partials[blockIdx.x * 2 + 1] = t2;
    }
}

__global__ __launch_bounds__(256) void jsd_reduce_kernel(
    const float* __restrict__ partials,
    float*       __restrict__ out)
{
    const int tid  = threadIdx.x;
    const int wave = tid >> 6;
    const int lane = tid & 63;

    float a = 0.0f, b = 0.0f;
    #pragma unroll
    for (int i = 0; i < NBLOCKS / 256; ++i) {
        a += partials[(i * 256 + tid) * 2 + 0];
        b += partials[(i * 256 + tid) * 2 + 1];
    }

    #pragma unroll
    for (int off = 32; off >= 1; off >>= 1) {
        a += __shfl_down(a, off, 64);
        b += __shfl_down(b, off, 64);
    }

    __shared__ float s1[4], s2[4];
    if (lane == 0) { s1[wave] = a; s2[wave] = b; }
    __syncthreads();

    if (tid == 0) {
        float t1 = s1[0] + s1[1] + s1[2] + s1[3];
        float t2 = s2[0] + s2[1] + s2[2] + s2[3];
        out[0] = sqrtf(t1) + sqrtf(t2);
    }
}

extern "C" void kernel_launch(void* const* d_in, const int* in_sizes, int n_in,
                              void* d_out, int out_size, void* d_ws, size_t ws_size,
                              hipStream_t stream) {
    const int*   b1 = (const int*)  d_in[0];
    const int*   b2 = (const int*)  d_in[1];
    const float* z1 = (const float*)d_in[2];
    const float* z2 = (const float*)d_in[3];
    const float* g1 = (const float*)d_in[4];
    const float* g2 = (const float*)d_in[5];
    float* out      = (float*)d_out;
    float* partials = (float*)d_ws;   // NBLOCKS*2 floats, fully overwritten

    jsd_dot_kernel<<<NBLOCKS, 256, 0, stream>>>(b1, b2, z1, z2, g1, g2, partials);
    jsd_reduce_kernel<<<1, 256, 0, stream>>>(partials, out);
}

// Round 4
// 154.637 us; speedup vs baseline: 3.5139x; 1.0301x over previous
//
#include <hip/hip_runtime.h>
#include <math.h>

// softplus(-p) = max(-p,0) + log(1+exp(-|p|)); fast intrinsics fine:
// threshold is 135 absolute on a ~6752 output (2%).
__device__ __forceinline__ float spn(float p) {
    return fmaxf(-p, 0.0f) + __logf(1.0f + __expf(-fabsf(p)));
}

__device__ __forceinline__ float dot4(float4 a, float4 b) {
    return a.x * b.x + a.y * b.y + a.z * b.z + a.w * b.w;
}

// Full 64-lane reduction, VALU-only (DPP). Result valid in lane 63.
// row_shr:1/2/4/8 within each 16-lane row, then row_bcast15 (rows 1,3 pick
// up rows 0,2 sums), row_bcast31 (upper half picks up lower half).
__device__ __forceinline__ float wave64_reduce(float x) {
    int t;
    t = __builtin_amdgcn_update_dpp(0, __builtin_bit_cast(int, x), 0x111, 0xf, 0xf, true);
    x += __builtin_bit_cast(float, t);
    t = __builtin_amdgcn_update_dpp(0, __builtin_bit_cast(int, x), 0x112, 0xf, 0xf, true);
    x += __builtin_bit_cast(float, t);
    t = __builtin_amdgcn_update_dpp(0, __builtin_bit_cast(int, x), 0x114, 0xf, 0xf, true);
    x += __builtin_bit_cast(float, t);
    t = __builtin_amdgcn_update_dpp(0, __builtin_bit_cast(int, x), 0x118, 0xf, 0xf, true);
    x += __builtin_bit_cast(float, t);
    t = __builtin_amdgcn_update_dpp(0, __builtin_bit_cast(int, x), 0x142, 0xa, 0xf, true); // row_bcast15
    x += __builtin_bit_cast(float, t);
    t = __builtin_amdgcn_update_dpp(0, __builtin_bit_cast(int, x), 0x143, 0xc, 0xf, true); // row_bcast31
    x += __builtin_bit_cast(float, t);
    return x;   // lane 63 holds the full sum
}

#define NBLOCKS 4096
#define NODES_PER_WAVE 4   // 4096 blocks * 4 waves * 4 nodes = 65536

// Wave-per-node loads: one node's 256-float row = exactly one wave64 float4
// load (1 KB contiguous). All 8 z-row loads issued up-front for max MLP.
__global__ __launch_bounds__(256) void jsd_dot_kernel(
    const int*   __restrict__ b1,
    const int*   __restrict__ b2,
    const float* __restrict__ z1,
    const float* __restrict__ z2,
    const float* __restrict__ g1,
    const float* __restrict__ g2,
    float*       __restrict__ partials)   // [NBLOCKS*2]
{
    const int wave = threadIdx.x >> 6;
    const int lane = threadIdx.x & 63;
    const int w    = blockIdx.x * 4 + wave;
    const int base = w * NODES_PER_WAVE;

    // Force wave-uniform node index -> scalar loads of b1/b2 (s_load),
    // SGPR-based g addressing.
    const int sbase = __builtin_amdgcn_readfirstlane(base);

    int i1[NODES_PER_WAVE], i2[NODES_PER_WAVE];
    #pragma unroll
    for (int j = 0; j < NODES_PER_WAVE; ++j) {
        i1[j] = b1[sbase + j];
        i2[j] = b2[sbase + j];
    }

    // Prefetch all z rows: 8 independent contiguous 1 KB loads in flight.
    float4 a1[NODES_PER_WAVE], a2[NODES_PER_WAVE];
    #pragma unroll
    for (int j = 0; j < NODES_PER_WAVE; ++j) {
        a1[j] = ((const float4*)(z1 + (size_t)(sbase + j) * 256))[lane];
        a2[j] = ((const float4*)(z2 + (size_t)(sbase + j) * 256))[lane];
    }

    float acc1 = 0.0f, acc2 = 0.0f;

    #pragma unroll
    for (int j = 0; j < NODES_PER_WAVE; ++j) {
        const float4 w11 = ((const float4*)(g1 + (size_t)i1[j] * 256))[lane];
        const float4 w12 = ((const float4*)(g2 + (size_t)i1[j] * 256))[lane];
        const float4 w22 = ((const float4*)(g2 + (size_t)i2[j] * 256))[lane];
        const float4 w21 = ((const float4*)(g1 + (size_t)i2[j] * 256))[lane];

        float s11 = wave64_reduce(dot4(a1[j], w11));
        float c12 = wave64_reduce(dot4(a1[j], w12));
        float s22 = wave64_reduce(dot4(a2[j], w22));
        float c21 = wave64_reduce(dot4(a2[j], w21));

        if (lane == 63) {
            // f(s)-f(c) = softplus(-c) - softplus(-s)
            float d1 = spn(c12) - spn(s11);
            float d2 = spn(c21) - spn(s22);
            acc1 += d1 * d1;
            acc2 += d2 * d2;
        }
    }

    __shared__ float s1[4], s2[4];
    if (lane == 63) { s1[wave] = acc1; s2[wave] = acc2; }
    __syncthreads();

    if (threadIdx.x == 0) {
        partials[blockIdx.x * 2 + 0] = s1[0] + s1[1] + s1[2] + s1[3];
        partials[blockIdx.x * 2 + 1] = s2[0] + s2[1] + s2[2] + s2[3];
    }
}

__global__ __launch_bounds__(256) void jsd_reduce_kernel(
    const float* __restrict__ partials,
    float*       __restrict__ out)
{
    const int tid  = threadIdx.x;
    const int wave = tid >> 6;
    const int lane = tid & 63;

    float a = 0.0f, b = 0.0f;
    #pragma unroll
    for (int i = 0; i < NBLOCKS / 256; ++i) {
        a += partials[(i * 256 + tid) * 2 + 0];
        b += partials[(i * 256 + tid) * 2 + 1];
    }

    a = wave64_reduce(a);
    b = wave64_reduce(b);

    __shared__ float s1[4], s2[4];
    if (lane == 63) { s1[wave] = a; s2[wave] = b; }
    __syncthreads();

    if (tid == 0) {
        float t1 = s1[0] + s1[1] + s1[2] + s1[3];
        float t2 = s2[0] + s2[1] + s2[2] + s2[3];
        out[0] = sqrtf(t1) + sqrtf(t2);
    }
}

extern "C" void kernel_launch(void* const* d_in, const int* in_sizes, int n_in,
                              void* d_out, int out_size, void* d_ws, size_t ws_size,
                              hipStream_t stream) {
    const int*   b1 = (const int*)  d_in[0];
    const int*   b2 = (const int*)  d_in[1];
    const float* z1 = (const float*)d_in[2];
    const float* z2 = (const float*)d_in[3];
    const float* g1 = (const float*)d_in[4];
    const float* g2 = (const float*)d_in[5];
    float* out      = (float*)d_out;
    float* partials = (float*)d_ws;   // NBLOCKS*2 floats, fully overwritten

    jsd_dot_kernel<<<NBLOCKS, 256, 0, stream>>>(b1, b2, z1, z2, g1, g2, partials);
    jsd_reduce_kernel<<<1, 256, 0, stream>>>(partials, out);
}